// Round 4
// baseline (780.458 us; speedup 1.0000x reference)
//
#include <hip/hip_runtime.h>
#include <hip/hip_bf16.h>
#include <cmath>

typedef unsigned short u16;
typedef __attribute__((ext_vector_type(8))) short bf16x8;
typedef __attribute__((ext_vector_type(4))) float f32x4;
typedef __attribute__((ext_vector_type(16))) float f32x16;
typedef __attribute__((ext_vector_type(2))) int i32x2;
typedef __attribute__((ext_vector_type(4))) unsigned int u32x4;

#define B_    2
#define S_    2048
#define H_    4096
#define NH_   32
#define NKV_  8
#define HD_   128
#define WIN_  1024

__device__ __forceinline__ u16 f2b(float f) {
  union { float f; unsigned u; } v; v.f = f;
  unsigned r = v.u + 0x7fffu + ((v.u >> 16) & 1u);
  return (u16)(r >> 16);
}
__device__ __forceinline__ float b2f(u16 h) {
  union { unsigned u; float f; } v; v.u = ((unsigned)h) << 16;
  return v.f;
}

__device__ __forceinline__ void storeC(float* p, float v) { *p = v; }
__device__ __forceinline__ void storeC(u16* p, float v)   { *p = f2b(v); }

// async global->LDS, 16B per lane; LDS dest must be wave-base + lane*16
__device__ __forceinline__ void gl2lds(const u16* g, u16* l) {
  __builtin_amdgcn_global_load_lds(
      (const __attribute__((address_space(1))) unsigned int*)(g),
      (__attribute__((address_space(3))) unsigned int*)(l), 16, 0, 0);
}

__device__ __forceinline__ i32x2 plswap(int a, int b) {
  return __builtin_amdgcn_permlane32_swap(a, b, false, false);
}
__device__ __forceinline__ unsigned pkbf16(float lo, float hi) {
  unsigned r;
  asm("v_cvt_pk_bf16_f32 %0, %1, %2" : "=v"(r) : "v"(lo), "v"(hi));
  return r;
}

// ---------------- fp32 -> bf16 conversion ----------------
__global__ __launch_bounds__(256) void cvt_bf16(const float* __restrict__ s,
                                                u16* __restrict__ d, int n4) {
  int i = blockIdx.x * 256 + threadIdx.x;
  if (i < n4) {
    float4 v = ((const float4*)s)[i];
    ushort4 o;
    o.x = f2b(v.x); o.y = f2b(v.y); o.z = f2b(v.z); o.w = f2b(v.w);
    ((ushort4*)d)[i] = o;
  }
}

// ---- small GEMM (K/V proj): C[M,N] = A[M,K]*W[N,K]^T, m97-style, BM x 128 --
template <int BM, typename OutT>
__global__ __launch_bounds__(256) void gemm_bt(const u16* __restrict__ A,
                                               const u16* __restrict__ W,
                                               OutT* __restrict__ C,
                                               int M, int N, int K) {
  __shared__ u16 As[BM * 32];
  __shared__ u16 Bs[128 * 32];
  const int t = threadIdx.x;
  const int lane = t & 63, wave = t >> 6;
  const int quad = lane >> 4, l16 = lane & 15;
  const int wm = wave >> 1, wn = wave & 1;
  constexpr int WM = BM / 2;
  constexpr int MI = WM / 16;
  const size_t m0 = (size_t)blockIdx.y * BM, n0 = (size_t)blockIdx.x * 128;

  f32x4 acc[MI][4] = {};
  const int srow = lane >> 2, skc = lane & 3;

  for (int k0 = 0; k0 < K; k0 += 32) {
    __syncthreads();
#pragma unroll
    for (int i = 0; i < BM / 64; i++) {
      int row = wave * (BM / 4) + i * 16 + srow;
      gl2lds(A + (m0 + row) * K + k0 + skc * 8, &As[row * 32 + skc * 8]);
    }
#pragma unroll
    for (int i = 0; i < 2; i++) {
      int row = wave * 32 + i * 16 + srow;
      gl2lds(W + (n0 + row) * K + k0 + skc * 8, &Bs[row * 32 + skc * 8]);
    }
    __syncthreads();
    bf16x8 af[MI], bfr[4];
#pragma unroll
    for (int i = 0; i < MI; i++)
      af[i] = *(const bf16x8*)(&As[(wm * WM + i * 16 + l16) * 32 + quad * 8]);
#pragma unroll
    for (int i = 0; i < 4; i++)
      bfr[i] = *(const bf16x8*)(&Bs[(wn * 64 + i * 16 + l16) * 32 + quad * 8]);
#pragma unroll
    for (int mi = 0; mi < MI; mi++)
#pragma unroll
      for (int nj = 0; nj < 4; nj++)
        acc[mi][nj] = __builtin_amdgcn_mfma_f32_16x16x32_bf16(
            af[mi], bfr[nj], acc[mi][nj], 0, 0, 0);
  }

#pragma unroll
  for (int mi = 0; mi < MI; mi++) {
    size_t rbase = m0 + wm * WM + mi * 16 + quad * 4;
#pragma unroll
    for (int nj = 0; nj < 4; nj++) {
      size_t col = n0 + wn * 64 + nj * 16 + l16;
#pragma unroll
      for (int e = 0; e < 4; e++)
        storeC(&C[(rbase + e) * N + col], acc[mi][nj][e]);
    }
  }
}

// ---- big GEMM: 256x256 tile, BK=32, 8 waves, T2 swizzle, counted vmcnt ----
// 4 LDS slots x (A[256][32] + B[256][32]) u16 = 128 KB; 2-tile lookahead.
// iter i: issue tile i+2 -> slot (i+2)&3 (last read 2 barriers ago), then
// s_waitcnt vmcnt(8) (tile i landed; tiles i+1,i+2 stay in flight), barrier,
// compute tile i, barrier. The wait targets loads issued a full iteration
// earlier -> near-zero stall; stage/compute pipeline.
// Swizzle: 16B-block j of 64B row holds global k-block j^(row&3); frag read
// XORs the same -> b128 reads at the 8-lane/16B-slot minimum (conflict-free).
template <typename OutT>
__global__ __launch_bounds__(512, 1) void gemm256(const u16* __restrict__ A,
                                                  const u16* __restrict__ W,
                                                  OutT* __restrict__ C,
                                                  int M, int N, int K) {
  __shared__ __align__(16) u16 smem[65536];  // 128 KB
  const int t = threadIdx.x;
  const int lane = t & 63, wave = t >> 6;
  const int quad = lane >> 4, l16 = lane & 15;
  const int wm = wave >> 2, wn = wave & 3;

  // XCD-chunked block swizzle (gridDim.x divisible by 8)
  const int wg = blockIdx.x;
  const int swz = (wg & 7) * ((int)gridDim.x >> 3) + (wg >> 3);
  const int nbn = N >> 8;
  const size_t m0 = (size_t)(swz / nbn) * 256, n0 = (size_t)(swz % nbn) * 256;

  f32x4 acc[8][4] = {};

  // staging: wave w covers rows 32w..32w+31 of A and of B; 2 instrs x 16 rows
  // lane: row = base + (lane>>2), j-block = lane&3, global k-block = j^(row&3)
  const int srow0 = wave * 32;
  const int sr = lane >> 2, sj = lane & 3;

  auto stage = [&](int slot, int kt) {
    u16* sb = smem + slot * 16384;  // A at +0, B at +8192 (u16 units)
#pragma unroll
    for (int half = 0; half < 2; half++) {
      int row = srow0 + half * 16 + sr;
      int gb = (sj ^ (row & 3)) * 8;
      gl2lds(A + (m0 + row) * K + kt + gb,
             sb + (srow0 + half * 16) * 32 + lane * 8);
      gl2lds(W + (n0 + row) * K + kt + gb,
             sb + 8192 + (srow0 + half * 16) * 32 + lane * 8);
    }
  };

  const int nk = K >> 5;
  stage(0, 0);
  stage(1, 32);
  for (int i = 0; i < nk; i++) {
    if (i + 2 < nk) stage((i + 2) & 3, (i + 2) << 5);
    if (i + 2 < nk) {
      asm volatile("s_waitcnt vmcnt(8)" ::: "memory");
    } else if (i + 1 < nk) {
      asm volatile("s_waitcnt vmcnt(4)" ::: "memory");
    } else {
      asm volatile("s_waitcnt vmcnt(0)" ::: "memory");
    }
    __builtin_amdgcn_sched_barrier(0);
    __builtin_amdgcn_s_barrier();

    const u16* ab = smem + (i & 3) * 16384;
    const u16* bb = ab + 8192;
    bf16x8 bfr[4];
#pragma unroll
    for (int nj = 0; nj < 4; nj++) {
      int row = wn * 64 + nj * 16 + l16;
      bfr[nj] = *(const bf16x8*)(bb + row * 32 + ((quad ^ (row & 3)) * 8));
    }
#pragma unroll
    for (int p = 0; p < 4; p++) {
      bf16x8 af[2];
#pragma unroll
      for (int mm = 0; mm < 2; mm++) {
        int row = wm * 128 + (p * 2 + mm) * 16 + l16;
        af[mm] = *(const bf16x8*)(ab + row * 32 + ((quad ^ (row & 3)) * 8));
      }
      __builtin_amdgcn_s_setprio(1);
#pragma unroll
      for (int mm = 0; mm < 2; mm++)
#pragma unroll
        for (int nj = 0; nj < 4; nj++)
          acc[p * 2 + mm][nj] = __builtin_amdgcn_mfma_f32_16x16x32_bf16(
              af[mm], bfr[nj], acc[p * 2 + mm][nj], 0, 0, 0);
      __builtin_amdgcn_s_setprio(0);
    }
    __builtin_amdgcn_sched_barrier(0);
    __builtin_amdgcn_s_barrier();
  }

#pragma unroll
  for (int mi = 0; mi < 8; mi++) {
    size_t rbase = m0 + wm * 128 + mi * 16 + quad * 4;
#pragma unroll
    for (int nj = 0; nj < 4; nj++) {
      size_t col = n0 + wn * 64 + nj * 16 + l16;
#pragma unroll
      for (int e = 0; e < 4; e++)
        storeC(&C[(rbase + e) * N + col], acc[mi][nj][e]);
    }
  }
}

// ---------------- RoPE in-place on bf16 [B*S, nh, 128] ----------------
__global__ __launch_bounds__(256) void rope_k(u16* __restrict__ X,
                                              const int* __restrict__ pos,
                                              int log2nh) {
  int idx = blockIdx.x * 256 + threadIdx.x;
  int i = idx & 63;
  int bsh = idx >> 6;
  int h = bsh & ((1 << log2nh) - 1);
  int bs = bsh >> log2nh;
  int p = pos[bs];
  float inv = exp2f(-(float)i * (13.287712379549449f / 64.0f));
  float ang = (float)p * inv;
  float sn, c;
  sincosf(ang, &sn, &c);
  size_t base = ((((size_t)bs) << log2nh) + h) * HD_;
  float x1 = b2f(X[base + i]), x2 = b2f(X[base + i + 64]);
  X[base + i]      = f2b(x1 * c - x2 * sn);
  X[base + i + 64] = f2b(x2 * c + x1 * sn);
}

// ------------- V transpose: [B,S,NKV,HD] -> [B,NKV,HD,S] -------------
__global__ __launch_bounds__(256) void transpose_v(const u16* __restrict__ V,
                                                   u16* __restrict__ Vt) {
  __shared__ u16 tile[64][72];
  int s0 = blockIdx.x * 64, d0 = blockIdx.y * 64, bh = blockIdx.z;
  int b = bh >> 3, hk = bh & 7;
  int t = threadIdx.x;
  int r = t >> 3, c = t & 7;
#pragma unroll
  for (int i = 0; i < 2; i++) {
    int row = r + i * 32;
    uint4 v = *(const uint4*)(V + (((size_t)(b * S_ + s0 + row)) * NKV_ + hk) * HD_ + d0 + c * 8);
    *(uint4*)(&tile[row][c * 8]) = v;
  }
  __syncthreads();
#pragma unroll
  for (int i = 0; i < 2; i++) {
    int d = r + i * 32;
    u16 tmp[8];
#pragma unroll
    for (int j = 0; j < 8; j++) tmp[j] = tile[c * 8 + j][d];
    *(uint4*)(Vt + ((size_t)bh * HD_ + d0 + d) * S_ + s0 + c * 8) = *(uint4*)tmp;
  }
}

// ---------------- flash attention, sliding window (swapped-QK 32x32) ------
__global__ __launch_bounds__(256, 2) void attn_k(const u16* __restrict__ Q,
                                                 const u16* __restrict__ K,
                                                 const u16* __restrict__ Vt,
                                                 u16* __restrict__ O) {
  __shared__ __align__(16) u16 smem[32768];  // 64 KB
  const int t = threadIdx.x, wave = t >> 6, lane = t & 63;
  const int cq = lane & 31, hi = lane >> 5;
  const int q0 = blockIdx.x * 128, h = blockIdx.y, b = blockIdx.z;
  const int hk = h >> 2;
  const int qw = q0 + wave * 32;
  const int q = qw + cq;
  const float SCL2 = 0.08838834764831845f * 1.4426950408889634f;  // scale*log2e

  bf16x8 qf[8];
  {
    const u16* qp = Q + ((size_t)(b * S_ + q) * NH_ + h) * HD_ + hi * 8;
#pragma unroll
    for (int c = 0; c < 8; c++) qf[c] = *(const bf16x8*)(qp + c * 16);
  }

  f32x16 oacc[4] = {};
  float m_i = -1e30f, l_i = 0.0f;

  const int rK = wave * 16 + (lane >> 4), jKl = lane & 15;
  const int rV = wave * 32 + (lane >> 3), jVl = lane & 7;
  const size_t kbase0 = (size_t)b * S_ * (NKV_ * HD_) + (size_t)hk * HD_;
  const size_t vbase0 = (size_t)(b * NKV_ + hk) * HD_ * S_;

  auto stage = [&](int bsel, int kt) {
    u16* kd = smem + bsel * 8192 + wave * 2048 + lane * 8;
    u16* vd = smem + 16384 + bsel * 8192 + wave * 2048 + lane * 8;
#pragma unroll
    for (int ii = 0; ii < 4; ii++) {
      int row = rK + 4 * ii;
      gl2lds(K + kbase0 + (size_t)(kt + row) * (NKV_ * HD_) + (jKl ^ (row & 7)) * 8,
             kd + ii * 512);
    }
#pragma unroll
    for (int ii = 0; ii < 4; ii++) {
      int row = rV + 8 * ii;
      gl2lds(Vt + vbase0 + (size_t)row * S_ + kt + (jVl ^ (row & 7)) * 8,
             vd + ii * 512);
    }
  };

  int lo = q0 - (WIN_ - 1); if (lo < 0) lo = 0;
  const int lo_t = lo & ~63;
  const int kt_max = q0 + 64;

  stage(0, lo_t);
  __syncthreads();
  int buf = 0;
  for (int kt = lo_t; kt <= kt_max; kt += 64) {
    if (kt + 64 <= kt_max) stage(buf ^ 1, kt + 64);
    if (kt <= qw + 31 && kt + 63 >= qw - (WIN_ - 1)) {
      const u16* ks = smem + buf * 8192;
      const u16* vs = smem + 16384 + buf * 8192;
      const int rx = cq & 7;
      f32x16 cs0 = {}, cs1 = {};
      __builtin_amdgcn_s_setprio(1);
#pragma unroll
      for (int c = 0; c < 8; c++) {
        const int blk = 2 * c + hi;
        bf16x8 a0 = *(const bf16x8*)(ks + cq * 128 + ((blk ^ rx) * 8));
        bf16x8 a1 = *(const bf16x8*)(ks + (32 + cq) * 128 + ((blk ^ rx) * 8));
        cs0 = __builtin_amdgcn_mfma_f32_32x32x16_bf16(a0, qf[c], cs0, 0, 0, 0);
        cs1 = __builtin_amdgcn_mfma_f32_32x32x16_bf16(a1, qf[c], cs1, 0, 0, 0);
      }
      __builtin_amdgcn_s_setprio(0);

      float sv[32];
      const bool full = (kt >= qw - 992) && (kt + 63 <= qw);
      if (full) {
#pragma unroll
        for (int r = 0; r < 16; r++) {
          sv[r] = cs0[r] * SCL2;
          sv[16 + r] = cs1[r] * SCL2;
        }
      } else {
#pragma unroll
        for (int g = 0; g < 2; g++)
#pragma unroll
          for (int r = 0; r < 16; r++) {
            int kk = kt + g * 32 + (r & 3) + 8 * (r >> 2) + 4 * hi;
            float s = (g ? cs1[r] : cs0[r]) * SCL2;
            sv[g * 16 + r] = (kk <= q && q - kk < WIN_) ? s : -1e30f;
          }
      }

      float m4[4] = {sv[0], sv[1], sv[2], sv[3]};
#pragma unroll
      for (int i = 4; i < 32; i++) m4[i & 3] = fmaxf(m4[i & 3], sv[i]);
      float mx = fmaxf(fmaxf(m4[0], m4[1]), fmaxf(m4[2], m4[3]));
      {
        i32x2 r2 = plswap(__float_as_int(mx), __float_as_int(mx));
        mx = fmaxf(__int_as_float(r2.x), __int_as_float(r2.y));
      }
      if (__any(mx > m_i + 8.0f)) {
        float mn = fmaxf(m_i, mx);
        float al = exp2f(m_i - mn);
        m_i = mn; l_i *= al;
#pragma unroll
        for (int dg = 0; dg < 4; dg++)
#pragma unroll
          for (int e = 0; e < 16; e++) oacc[dg][e] *= al;
      }
      float p[32], a4[4] = {0.f, 0.f, 0.f, 0.f};
#pragma unroll
      for (int i = 0; i < 32; i++) {
        p[i] = exp2f(sv[i] - m_i);
        a4[i & 3] += p[i];
      }
      float rs = (a4[0] + a4[1]) + (a4[2] + a4[3]);
      {
        i32x2 r2 = plswap(__float_as_int(rs), __float_as_int(rs));
        rs = __int_as_float(r2.x) + __int_as_float(r2.y);
      }
      l_i += rs;

      bf16x8 pb[4];
#pragma unroll
      for (int cc = 0; cc < 4; cc++) {
        const int bse = cc * 8;
        unsigned x0 = pkbf16(p[bse + 0], p[bse + 1]);
        unsigned y0 = pkbf16(p[bse + 4], p[bse + 5]);
        unsigned x1 = pkbf16(p[bse + 2], p[bse + 3]);
        unsigned y1 = pkbf16(p[bse + 6], p[bse + 7]);
        i32x2 w02 = plswap((int)x0, (int)y0);
        i32x2 w13 = plswap((int)x1, (int)y1);
        u32x4 wv;
        wv.x = (unsigned)w02.x; wv.y = (unsigned)w13.x;
        wv.z = (unsigned)w02.y; wv.w = (unsigned)w13.y;
        pb[cc] = __builtin_bit_cast(bf16x8, wv);
      }

      __builtin_amdgcn_s_setprio(1);
#pragma unroll
      for (int dg = 0; dg < 4; dg++) {
        const int rr = dg * 32 + cq;
#pragma unroll
        for (int cc = 0; cc < 4; cc++) {
          bf16x8 va = *(const bf16x8*)(vs + rr * 64 + (((2 * cc + hi) ^ (rr & 7)) * 8));
          oacc[dg] = __builtin_amdgcn_mfma_f32_32x32x16_bf16(va, pb[cc], oacc[dg], 0, 0, 0);
        }
      }
      __builtin_amdgcn_s_setprio(0);
    }
    __syncthreads();
    buf ^= 1;
  }

  const float inv = 1.0f / l_i;
  u16* os = smem + wave * 4352;  // [32 q][136 u16] padded rows
#pragma unroll
  for (int dg = 0; dg < 4; dg++)
#pragma unroll
    for (int e = 0; e < 16; e += 2) {
      int d = dg * 32 + (e & 3) + 8 * (e >> 2) + 4 * hi;
      unsigned pk2 = (unsigned)f2b(oacc[dg][e] * inv) |
                     ((unsigned)f2b(oacc[dg][e + 1] * inv) << 16);
      *(unsigned*)(os + cq * 136 + d) = pk2;
    }
  asm volatile("s_waitcnt lgkmcnt(0)" ::: "memory");
  __builtin_amdgcn_sched_barrier(0);
#pragma unroll
  for (int ps = 0; ps < 8; ps++) {
    int row = (lane >> 4) + ps * 4, j = lane & 15;
    uint4 vv = *(const uint4*)(os + row * 136 + j * 8);
    *(uint4*)(O + ((size_t)(b * S_ + q0 + wave * 32 + row) * NH_ + h) * HD_ + j * 8) = vv;
  }
}

// ---------------- launch ----------------
extern "C" void kernel_launch(void* const* d_in, const int* in_sizes, int n_in,
                              void* d_out, int out_size, void* d_ws, size_t ws_size,
                              hipStream_t stream) {
  const float* x  = (const float*)d_in[0];
  const float* Wq = (const float*)d_in[1];
  const float* Wk = (const float*)d_in[2];
  const float* Wv = (const float*)d_in[3];
  const float* Wo = (const float*)d_in[4];
  const int*  pos = (const int*)d_in[5];
  float* out = (float*)d_out;

  const size_t BS = (size_t)B_ * S_;  // 4096
  const size_t MB = 1024 * 1024;
  char* p = (char*)d_ws;
  u16* xb  = (u16*)(p);             // 32 MB: x bf16; later Wo bf16
  u16* W32 = (u16*)(p + 32 * MB);   // 32 MB: Wq bf16; later attn-out Ob
  u16* W8  = (u16*)(p + 64 * MB);   // 8 MB: Wk, then Wv, then Vt
  u16* Qb  = (u16*)(p + 72 * MB);   // 32 MB
  u16* Kb  = (u16*)(p + 104 * MB);  // 8 MB
  u16* Vb  = (u16*)(p + 112 * MB);  // 8 MB
  u16* WoB = xb;
  u16* Ob  = W32;
  u16* Vt  = W8;

  auto cvt = [&](const float* src, u16* dst, size_t n) {
    int n4 = (int)(n / 4);
    cvt_bf16<<<dim3((n4 + 255) / 256), dim3(256), 0, stream>>>(src, dst, n4);
  };

  cvt(x, xb, BS * H_);
  cvt(Wq, W32, (size_t)H_ * H_);
  gemm256<u16><<<dim3(256), dim3(512), 0, stream>>>(xb, W32, Qb, (int)BS, H_, H_);
  cvt(Wk, W8, (size_t)NKV_ * HD_ * H_);
  gemm_bt<64, u16><<<dim3(NKV_ * HD_ / 128, BS / 64), dim3(256), 0, stream>>>(
      xb, W8, Kb, (int)BS, NKV_ * HD_, H_);
  cvt(Wv, W8, (size_t)NKV_ * HD_ * H_);
  gemm_bt<64, u16><<<dim3(NKV_ * HD_ / 128, BS / 64), dim3(256), 0, stream>>>(
      xb, W8, Vb, (int)BS, NKV_ * HD_, H_);

  rope_k<<<dim3((int)(BS * NH_ * 64 / 256)), dim3(256), 0, stream>>>(Qb, pos, 5);
  rope_k<<<dim3((int)(BS * NKV_ * 64 / 256)), dim3(256), 0, stream>>>(Kb, pos, 3);

  transpose_v<<<dim3(S_ / 64, HD_ / 64, B_ * NKV_), dim3(256), 0, stream>>>(Vb, Vt);

  attn_k<<<dim3(S_ / 128, NH_, B_), dim3(256), 0, stream>>>(Qb, Kb, Vt, Ob);

  cvt(Wo, WoB, (size_t)H_ * H_);
  gemm256<float><<<dim3(256), dim3(512), 0, stream>>>(Ob, WoB, out, (int)BS, H_, H_);
}

// Round 5
// 763.506 us; speedup vs baseline: 1.0222x; 1.0222x over previous
//
#include <hip/hip_runtime.h>
#include <hip/hip_bf16.h>
#include <cmath>

typedef unsigned short u16;
typedef __attribute__((ext_vector_type(8))) short bf16x8;
typedef __attribute__((ext_vector_type(4))) float f32x4;
typedef __attribute__((ext_vector_type(16))) float f32x16;
typedef __attribute__((ext_vector_type(2))) int i32x2;
typedef __attribute__((ext_vector_type(4))) unsigned int u32x4;

#define B_    2
#define S_    2048
#define H_    4096
#define NH_   32
#define NKV_  8
#define HD_   128
#define WIN_  1024

__device__ __forceinline__ u16 f2b(float f) {
  union { float f; unsigned u; } v; v.f = f;
  unsigned r = v.u + 0x7fffu + ((v.u >> 16) & 1u);
  return (u16)(r >> 16);
}
__device__ __forceinline__ float b2f(u16 h) {
  union { unsigned u; float f; } v; v.u = ((unsigned)h) << 16;
  return v.f;
}

__device__ __forceinline__ void storeC(float* p, float v) { *p = v; }
__device__ __forceinline__ void storeC(u16* p, float v)   { *p = f2b(v); }

// async global->LDS, 16B per lane; LDS dest must be wave-base + lane*16
__device__ __forceinline__ void gl2lds(const u16* g, u16* l) {
  __builtin_amdgcn_global_load_lds(
      (const __attribute__((address_space(1))) unsigned int*)(g),
      (__attribute__((address_space(3))) unsigned int*)(l), 16, 0, 0);
}

__device__ __forceinline__ i32x2 plswap(int a, int b) {
  return __builtin_amdgcn_permlane32_swap(a, b, false, false);
}
__device__ __forceinline__ unsigned pkbf16(float lo, float hi) {
  unsigned r;
  asm("v_cvt_pk_bf16_f32 %0, %1, %2" : "=v"(r) : "v"(lo), "v"(hi));
  return r;
}

// ---------------- fp32 -> bf16 conversion ----------------
__global__ __launch_bounds__(256) void cvt_bf16(const float* __restrict__ s,
                                                u16* __restrict__ d, int n4) {
  int i = blockIdx.x * 256 + threadIdx.x;
  if (i < n4) {
    float4 v = ((const float4*)s)[i];
    ushort4 o;
    o.x = f2b(v.x); o.y = f2b(v.y); o.z = f2b(v.z); o.w = f2b(v.w);
    ((ushort4*)d)[i] = o;
  }
}

// ---- small GEMM (K/V proj): C[M,N] = A[M,K]*W[N,K]^T, m97-style, BM x 128 --
template <int BM, typename OutT>
__global__ __launch_bounds__(256) void gemm_bt(const u16* __restrict__ A,
                                               const u16* __restrict__ W,
                                               OutT* __restrict__ C,
                                               int M, int N, int K) {
  __shared__ u16 As[BM * 32];
  __shared__ u16 Bs[128 * 32];
  const int t = threadIdx.x;
  const int lane = t & 63, wave = t >> 6;
  const int quad = lane >> 4, l16 = lane & 15;
  const int wm = wave >> 1, wn = wave & 1;
  constexpr int WM = BM / 2;
  constexpr int MI = WM / 16;
  const size_t m0 = (size_t)blockIdx.y * BM, n0 = (size_t)blockIdx.x * 128;

  f32x4 acc[MI][4] = {};
  const int srow = lane >> 2, skc = lane & 3;

  for (int k0 = 0; k0 < K; k0 += 32) {
    __syncthreads();
#pragma unroll
    for (int i = 0; i < BM / 64; i++) {
      int row = wave * (BM / 4) + i * 16 + srow;
      gl2lds(A + (m0 + row) * K + k0 + skc * 8, &As[row * 32 + skc * 8]);
    }
#pragma unroll
    for (int i = 0; i < 2; i++) {
      int row = wave * 32 + i * 16 + srow;
      gl2lds(W + (n0 + row) * K + k0 + skc * 8, &Bs[row * 32 + skc * 8]);
    }
    __syncthreads();
    bf16x8 af[MI], bfr[4];
#pragma unroll
    for (int i = 0; i < MI; i++)
      af[i] = *(const bf16x8*)(&As[(wm * WM + i * 16 + l16) * 32 + quad * 8]);
#pragma unroll
    for (int i = 0; i < 4; i++)
      bfr[i] = *(const bf16x8*)(&Bs[(wn * 64 + i * 16 + l16) * 32 + quad * 8]);
#pragma unroll
    for (int mi = 0; mi < MI; mi++)
#pragma unroll
      for (int nj = 0; nj < 4; nj++)
        acc[mi][nj] = __builtin_amdgcn_mfma_f32_16x16x32_bf16(
            af[mi], bfr[nj], acc[mi][nj], 0, 0, 0);
  }

#pragma unroll
  for (int mi = 0; mi < MI; mi++) {
    size_t rbase = m0 + wm * WM + mi * 16 + quad * 4;
#pragma unroll
    for (int nj = 0; nj < 4; nj++) {
      size_t col = n0 + wn * 64 + nj * 16 + l16;
#pragma unroll
      for (int e = 0; e < 4; e++)
        storeC(&C[(rbase + e) * N + col], acc[mi][nj][e]);
    }
  }
}

// ---- big GEMM: 256x256 tile, BK=64, 8 waves, T2 swizzle, counted vmcnt ----
// LDS (u16 units): As[2][256][64] at 0, Bs[2][256][64] at 32768. 128 KB.
// Round-3 layout/swizzle (verified conflict-free) + T4 pipelining:
//   iter i: stage(i+1) [8 loads]; s_waitcnt vmcnt(8) -> only tile i's loads
//   (issued LAST iter) are drained, tile i+1's stay in flight across the
//   barrier; raw s_barrier; compute tile i; raw s_barrier (protects slot
//   i+1 from next iter's stage overwrite; no counter drain).
template <typename OutT>
__global__ __launch_bounds__(512, 1) void gemm256(const u16* __restrict__ A,
                                                  const u16* __restrict__ W,
                                                  OutT* __restrict__ C,
                                                  int M, int N, int K) {
  __shared__ __align__(16) u16 smem[65536];  // 128 KB
  const int t = threadIdx.x;
  const int lane = t & 63, wave = t >> 6;
  const int quad = lane >> 4, l16 = lane & 15;
  const int wm = wave >> 2, wn = wave & 3;

  // XCD-chunked block swizzle (gridDim.x divisible by 8)
  const int wg = blockIdx.x;
  const int swz = (wg & 7) * ((int)gridDim.x >> 3) + (wg >> 3);
  const int nbn = N >> 8;
  const size_t m0 = (size_t)(swz / nbn) * 256, n0 = (size_t)(swz % nbn) * 256;

  f32x4 acc[8][4] = {};

  const int srow0 = wave * 32;          // wave's 32-row staging stripe
  const int sr = lane >> 3, sj = lane & 7;

  auto stage = [&](int bsel, int kt) {
    u16* ab = smem + bsel * 16384;
    u16* bb = smem + 32768 + bsel * 16384;
#pragma unroll
    for (int ii = 0; ii < 4; ii++) {
      int row = srow0 + ii * 8 + sr;
      int gb = (sj ^ (row & 7)) * 8;     // pre-swizzled global k-block
      gl2lds(A + (m0 + row) * K + kt + gb, ab + (srow0 + ii * 8) * 64 + lane * 8);
      gl2lds(W + (n0 + row) * K + kt + gb, bb + (srow0 + ii * 8) * 64 + lane * 8);
    }
  };

  const int nk = K >> 6;
  stage(0, 0);
  int buf = 0;
  for (int i = 0; i < nk; i++) {
    if (i + 1 < nk) {
      stage(buf ^ 1, (i + 1) << 6);
      asm volatile("s_waitcnt vmcnt(8)" ::: "memory");
    } else {
      asm volatile("s_waitcnt vmcnt(0)" ::: "memory");
    }
    __builtin_amdgcn_sched_barrier(0);
    __builtin_amdgcn_s_barrier();

    const u16* ab = smem + buf * 16384;
    const u16* bb = smem + 32768 + buf * 16384;

    bf16x8 bfr[4][2];
#pragma unroll
    for (int nj = 0; nj < 4; nj++) {
      int row = wn * 64 + nj * 16 + l16;
#pragma unroll
      for (int ks = 0; ks < 2; ks++)
        bfr[nj][ks] = *(const bf16x8*)(bb + row * 64 + (((ks * 4 + quad) ^ (row & 7)) * 8));
    }
#pragma unroll
    for (int p = 0; p < 4; p++) {
      bf16x8 af[2][2];
#pragma unroll
      for (int mm = 0; mm < 2; mm++) {
        int row = wm * 128 + (p * 2 + mm) * 16 + l16;
#pragma unroll
        for (int ks = 0; ks < 2; ks++)
          af[mm][ks] = *(const bf16x8*)(ab + row * 64 + (((ks * 4 + quad) ^ (row & 7)) * 8));
      }
      __builtin_amdgcn_s_setprio(1);
#pragma unroll
      for (int mm = 0; mm < 2; mm++)
#pragma unroll
        for (int nj = 0; nj < 4; nj++)
#pragma unroll
          for (int ks = 0; ks < 2; ks++)
            acc[p * 2 + mm][nj] = __builtin_amdgcn_mfma_f32_16x16x32_bf16(
                af[mm][ks], bfr[nj][ks], acc[p * 2 + mm][nj], 0, 0, 0);
      __builtin_amdgcn_s_setprio(0);
    }
    __builtin_amdgcn_s_barrier();
    buf ^= 1;
  }

#pragma unroll
  for (int mi = 0; mi < 8; mi++) {
    size_t rbase = m0 + wm * 128 + mi * 16 + quad * 4;
#pragma unroll
    for (int nj = 0; nj < 4; nj++) {
      size_t col = n0 + wn * 64 + nj * 16 + l16;
#pragma unroll
      for (int e = 0; e < 4; e++)
        storeC(&C[(rbase + e) * N + col], acc[mi][nj][e]);
    }
  }
}

// ---------------- RoPE in-place on bf16 [B*S, nh, 128] ----------------
__global__ __launch_bounds__(256) void rope_k(u16* __restrict__ X,
                                              const int* __restrict__ pos,
                                              int log2nh) {
  int idx = blockIdx.x * 256 + threadIdx.x;
  int i = idx & 63;
  int bsh = idx >> 6;
  int h = bsh & ((1 << log2nh) - 1);
  int bs = bsh >> log2nh;
  int p = pos[bs];
  float inv = exp2f(-(float)i * (13.287712379549449f / 64.0f));
  float ang = (float)p * inv;
  float sn, c;
  sincosf(ang, &sn, &c);
  size_t base = ((((size_t)bs) << log2nh) + h) * HD_;
  float x1 = b2f(X[base + i]), x2 = b2f(X[base + i + 64]);
  X[base + i]      = f2b(x1 * c - x2 * sn);
  X[base + i + 64] = f2b(x2 * c + x1 * sn);
}

// ------------- V transpose: [B,S,NKV,HD] -> [B,NKV,HD,S] -------------
__global__ __launch_bounds__(256) void transpose_v(const u16* __restrict__ V,
                                                   u16* __restrict__ Vt) {
  __shared__ u16 tile[64][72];
  int s0 = blockIdx.x * 64, d0 = blockIdx.y * 64, bh = blockIdx.z;
  int b = bh >> 3, hk = bh & 7;
  int t = threadIdx.x;
  int r = t >> 3, c = t & 7;
#pragma unroll
  for (int i = 0; i < 2; i++) {
    int row = r + i * 32;
    uint4 v = *(const uint4*)(V + (((size_t)(b * S_ + s0 + row)) * NKV_ + hk) * HD_ + d0 + c * 8);
    *(uint4*)(&tile[row][c * 8]) = v;
  }
  __syncthreads();
#pragma unroll
  for (int i = 0; i < 2; i++) {
    int d = r + i * 32;
    u16 tmp[8];
#pragma unroll
    for (int j = 0; j < 8; j++) tmp[j] = tile[c * 8 + j][d];
    *(uint4*)(Vt + ((size_t)bh * HD_ + d0 + d) * S_ + s0 + c * 8) = *(uint4*)tmp;
  }
}

// ---------------- flash attention, sliding window (swapped-QK 32x32) ------
// Same counted-vmcnt sync as gemm256: stage(next) -> vmcnt(8) -> barrier ->
// compute -> barrier. 8 loads/thread/tile.
__global__ __launch_bounds__(256, 2) void attn_k(const u16* __restrict__ Q,
                                                 const u16* __restrict__ K,
                                                 const u16* __restrict__ Vt,
                                                 u16* __restrict__ O) {
  __shared__ __align__(16) u16 smem[32768];  // 64 KB
  const int t = threadIdx.x, wave = t >> 6, lane = t & 63;
  const int cq = lane & 31, hi = lane >> 5;
  const int q0 = blockIdx.x * 128, h = blockIdx.y, b = blockIdx.z;
  const int hk = h >> 2;
  const int qw = q0 + wave * 32;
  const int q = qw + cq;
  const float SCL2 = 0.08838834764831845f * 1.4426950408889634f;  // scale*log2e

  bf16x8 qf[8];
  {
    const u16* qp = Q + ((size_t)(b * S_ + q) * NH_ + h) * HD_ + hi * 8;
#pragma unroll
    for (int c = 0; c < 8; c++) qf[c] = *(const bf16x8*)(qp + c * 16);
  }

  f32x16 oacc[4] = {};
  float m_i = -1e30f, l_i = 0.0f;

  const int rK = wave * 16 + (lane >> 4), jKl = lane & 15;
  const int rV = wave * 32 + (lane >> 3), jVl = lane & 7;
  const size_t kbase0 = (size_t)b * S_ * (NKV_ * HD_) + (size_t)hk * HD_;
  const size_t vbase0 = (size_t)(b * NKV_ + hk) * HD_ * S_;

  auto stage = [&](int bsel, int kt) {
    u16* kd = smem + bsel * 8192 + wave * 2048 + lane * 8;
    u16* vd = smem + 16384 + bsel * 8192 + wave * 2048 + lane * 8;
#pragma unroll
    for (int ii = 0; ii < 4; ii++) {
      int row = rK + 4 * ii;
      gl2lds(K + kbase0 + (size_t)(kt + row) * (NKV_ * HD_) + (jKl ^ (row & 7)) * 8,
             kd + ii * 512);
    }
#pragma unroll
    for (int ii = 0; ii < 4; ii++) {
      int row = rV + 8 * ii;
      gl2lds(Vt + vbase0 + (size_t)row * S_ + kt + (jVl ^ (row & 7)) * 8,
             vd + ii * 512);
    }
  };

  int lo = q0 - (WIN_ - 1); if (lo < 0) lo = 0;
  const int lo_t = lo & ~63;
  const int kt_max = q0 + 64;

  stage(0, lo_t);
  int buf = 0;
  for (int kt = lo_t; kt <= kt_max; kt += 64) {
    if (kt + 64 <= kt_max) {
      stage(buf ^ 1, kt + 64);
      asm volatile("s_waitcnt vmcnt(8)" ::: "memory");
    } else {
      asm volatile("s_waitcnt vmcnt(0)" ::: "memory");
    }
    __builtin_amdgcn_sched_barrier(0);
    __builtin_amdgcn_s_barrier();
    if (kt <= qw + 31 && kt + 63 >= qw - (WIN_ - 1)) {
      const u16* ks = smem + buf * 8192;
      const u16* vs = smem + 16384 + buf * 8192;
      const int rx = cq & 7;
      f32x16 cs0 = {}, cs1 = {};
      __builtin_amdgcn_s_setprio(1);
#pragma unroll
      for (int c = 0; c < 8; c++) {
        const int blk = 2 * c + hi;
        bf16x8 a0 = *(const bf16x8*)(ks + cq * 128 + ((blk ^ rx) * 8));
        bf16x8 a1 = *(const bf16x8*)(ks + (32 + cq) * 128 + ((blk ^ rx) * 8));
        cs0 = __builtin_amdgcn_mfma_f32_32x32x16_bf16(a0, qf[c], cs0, 0, 0, 0);
        cs1 = __builtin_amdgcn_mfma_f32_32x32x16_bf16(a1, qf[c], cs1, 0, 0, 0);
      }
      __builtin_amdgcn_s_setprio(0);

      float sv[32];
      const bool full = (kt >= qw - 992) && (kt + 63 <= qw);
      if (full) {
#pragma unroll
        for (int r = 0; r < 16; r++) {
          sv[r] = cs0[r] * SCL2;
          sv[16 + r] = cs1[r] * SCL2;
        }
      } else {
#pragma unroll
        for (int g = 0; g < 2; g++)
#pragma unroll
          for (int r = 0; r < 16; r++) {
            int kk = kt + g * 32 + (r & 3) + 8 * (r >> 2) + 4 * hi;
            float s = (g ? cs1[r] : cs0[r]) * SCL2;
            sv[g * 16 + r] = (kk <= q && q - kk < WIN_) ? s : -1e30f;
          }
      }

      float m4[4] = {sv[0], sv[1], sv[2], sv[3]};
#pragma unroll
      for (int i = 4; i < 32; i++) m4[i & 3] = fmaxf(m4[i & 3], sv[i]);
      float mx = fmaxf(fmaxf(m4[0], m4[1]), fmaxf(m4[2], m4[3]));
      {
        i32x2 r2 = plswap(__float_as_int(mx), __float_as_int(mx));
        mx = fmaxf(__int_as_float(r2.x), __int_as_float(r2.y));
      }
      if (__any(mx > m_i + 8.0f)) {
        float mn = fmaxf(m_i, mx);
        float al = exp2f(m_i - mn);
        m_i = mn; l_i *= al;
#pragma unroll
        for (int dg = 0; dg < 4; dg++)
#pragma unroll
          for (int e = 0; e < 16; e++) oacc[dg][e] *= al;
      }
      float p[32], a4[4] = {0.f, 0.f, 0.f, 0.f};
#pragma unroll
      for (int i = 0; i < 32; i++) {
        p[i] = exp2f(sv[i] - m_i);
        a4[i & 3] += p[i];
      }
      float rs = (a4[0] + a4[1]) + (a4[2] + a4[3]);
      {
        i32x2 r2 = plswap(__float_as_int(rs), __float_as_int(rs));
        rs = __int_as_float(r2.x) + __int_as_float(r2.y);
      }
      l_i += rs;

      bf16x8 pb[4];
#pragma unroll
      for (int cc = 0; cc < 4; cc++) {
        const int bse = cc * 8;
        unsigned x0 = pkbf16(p[bse + 0], p[bse + 1]);
        unsigned y0 = pkbf16(p[bse + 4], p[bse + 5]);
        unsigned x1 = pkbf16(p[bse + 2], p[bse + 3]);
        unsigned y1 = pkbf16(p[bse + 6], p[bse + 7]);
        i32x2 w02 = plswap((int)x0, (int)y0);
        i32x2 w13 = plswap((int)x1, (int)y1);
        u32x4 wv;
        wv.x = (unsigned)w02.x; wv.y = (unsigned)w13.x;
        wv.z = (unsigned)w02.y; wv.w = (unsigned)w13.y;
        pb[cc] = __builtin_bit_cast(bf16x8, wv);
      }

      __builtin_amdgcn_s_setprio(1);
#pragma unroll
      for (int dg = 0; dg < 4; dg++) {
        const int rr = dg * 32 + cq;
#pragma unroll
        for (int cc = 0; cc < 4; cc++) {
          bf16x8 va = *(const bf16x8*)(vs + rr * 64 + (((2 * cc + hi) ^ (rr & 7)) * 8));
          oacc[dg] = __builtin_amdgcn_mfma_f32_32x32x16_bf16(va, pb[cc], oacc[dg], 0, 0, 0);
        }
      }
      __builtin_amdgcn_s_setprio(0);
    }
    __builtin_amdgcn_s_barrier();
    buf ^= 1;
  }

  const float inv = 1.0f / l_i;
  u16* os = smem + wave * 4352;  // [32 q][136 u16] padded rows
#pragma unroll
  for (int dg = 0; dg < 4; dg++)
#pragma unroll
    for (int e = 0; e < 16; e += 2) {
      int d = dg * 32 + (e & 3) + 8 * (e >> 2) + 4 * hi;
      unsigned pk2 = (unsigned)f2b(oacc[dg][e] * inv) |
                     ((unsigned)f2b(oacc[dg][e + 1] * inv) << 16);
      *(unsigned*)(os + cq * 136 + d) = pk2;
    }
  asm volatile("s_waitcnt lgkmcnt(0)" ::: "memory");
  __builtin_amdgcn_sched_barrier(0);
#pragma unroll
  for (int ps = 0; ps < 8; ps++) {
    int row = (lane >> 4) + ps * 4, j = lane & 15;
    uint4 vv = *(const uint4*)(os + row * 136 + j * 8);
    *(uint4*)(O + ((size_t)(b * S_ + q0 + wave * 32 + row) * NH_ + h) * HD_ + j * 8) = vv;
  }
}

// ---------------- launch ----------------
extern "C" void kernel_launch(void* const* d_in, const int* in_sizes, int n_in,
                              void* d_out, int out_size, void* d_ws, size_t ws_size,
                              hipStream_t stream) {
  const float* x  = (const float*)d_in[0];
  const float* Wq = (const float*)d_in[1];
  const float* Wk = (const float*)d_in[2];
  const float* Wv = (const float*)d_in[3];
  const float* Wo = (const float*)d_in[4];
  const int*  pos = (const int*)d_in[5];
  float* out = (float*)d_out;

  const size_t BS = (size_t)B_ * S_;  // 4096
  const size_t MB = 1024 * 1024;
  char* p = (char*)d_ws;
  u16* xb  = (u16*)(p);             // 32 MB: x bf16; later Wo bf16
  u16* W32 = (u16*)(p + 32 * MB);   // 32 MB: Wq bf16; later attn-out Ob
  u16* W8  = (u16*)(p + 64 * MB);   // 8 MB: Wk, then Wv, then Vt
  u16* Qb  = (u16*)(p + 72 * MB);   // 32 MB
  u16* Kb  = (u16*)(p + 104 * MB);  // 8 MB
  u16* Vb  = (u16*)(p + 112 * MB);  // 8 MB
  u16* WoB = xb;
  u16* Ob  = W32;
  u16* Vt  = W8;

  auto cvt = [&](const float* src, u16* dst, size_t n) {
    int n4 = (int)(n / 4);
    cvt_bf16<<<dim3((n4 + 255) / 256), dim3(256), 0, stream>>>(src, dst, n4);
  };

  cvt(x, xb, BS * H_);
  cvt(Wq, W32, (size_t)H_ * H_);
  gemm256<u16><<<dim3(256), dim3(512), 0, stream>>>(xb, W32, Qb, (int)BS, H_, H_);
  cvt(Wk, W8, (size_t)NKV_ * HD_ * H_);
  gemm_bt<64, u16><<<dim3(NKV_ * HD_ / 128, BS / 64), dim3(256), 0, stream>>>(
      xb, W8, Kb, (int)BS, NKV_ * HD_, H_);
  cvt(Wv, W8, (size_t)NKV_ * HD_ * H_);
  gemm_bt<64, u16><<<dim3(NKV_ * HD_ / 128, BS / 64), dim3(256), 0, stream>>>(
      xb, W8, Vb, (int)BS, NKV_ * HD_, H_);

  rope_k<<<dim3((int)(BS * NH_ * 64 / 256)), dim3(256), 0, stream>>>(Qb, pos, 5);
  rope_k<<<dim3((int)(BS * NKV_ * 64 / 256)), dim3(256), 0, stream>>>(Kb, pos, 3);

  transpose_v<<<dim3(S_ / 64, HD_ / 64, B_ * NKV_), dim3(256), 0, stream>>>(Vb, Vt);

  attn_k<<<dim3(S_ / 128, NH_, B_), dim3(256), 0, stream>>>(Qb, Kb, Vt, Ob);

  cvt(Wo, WoB, (size_t)H_ * H_);
  gemm256<float><<<dim3(256), dim3(512), 0, stream>>>(Ob, WoB, out, (int)BS, H_, H_);
}